// Round 10
// baseline (113.480 us; speedup 1.0000x reference)
//
#include <hip/hip_runtime.h>

// GarNet: B=64 V=4096 F=16 A=8 P=16 NF=16. Inputs f32 (R2-confirmed), output f32.
// R9 lesson: fused kernel correct but ~25us — the spin loop polled with
// agent-scope ACQUIRE, emitting a buffer_inv per iteration (8 thr x 512 blk x
// 1000s iters of cache invalidates = memory-pipe thrash for co-resident waves).
// R10: poll RELAXED, then ONE agent acquire fence before reading partials.
// Everything else identical to R9: 512 blocks = 2/CU (co-resident, deadlock-free
// spin; bounded), e[v][8] persists in LDS across the barrier, epilogue LDS->out.
//
//   G[b,a,f]=sum_v ew*d, E=sum_v ew ; agg=(Wflr^T G + bflr E)/V ; M=agg*Wout
//   out[v,n]= mask*bout[n] + sum_a ew[v,a]*M[a,n]      (e==0 when masked)

#define B_ 64
#define V_ 4096
#define F_ 16
#define A_ 8
#define P_ 16
#define NF_ 16
#define SPB 8                 // blocks per batch
#define NBLK (B_*SPB)         // 512 blocks = 2 per CU
#define VPB (V_/SPB)          // 512 vertices per block
#define GE_ (A_*F_ + A_)      // 136 partials per block
#define ESTR 12               // e_lds row stride (floats)
#define DSTR 20               // d_lds row stride (floats)
#define GSL 132               // gred slice stride (8 groups * 16 + 4 pad)
#define MAGIC 0x5CA1AB1Eu

typedef unsigned int uint32;
typedef unsigned short u16;

__device__ __forceinline__ float bflo(uint32 u){ union{uint32 i;float f;}x; x.i=u<<16; return x.f; }
__device__ __forceinline__ float bfhi(uint32 u){ union{uint32 i;float f;}x; x.i=u&0xffff0000u; return x.f; }

// dtype probe (R2: votes f32 on this harness; kept as cheap insurance)
__device__ __forceinline__ bool detect_bf16(const void* data){
  const uint32* w = (const uint32*)data;
  int c = 0;
  #pragma unroll
  for (int i=0;i<16;++i){
    uint32 e = (w[i]>>7) & 0xffu;
    c += (e>=100u && e<=135u) ? 1 : 0;
  }
  return c >= 11;
}

template<bool BF16>
__device__ __forceinline__ float ldw(const void* p, int i){
  return BF16 ? bflo((uint32)((const u16*)p)[i]) : ((const float*)p)[i];
}

template<bool BF16>
__device__ __forceinline__ void load_vertex(const void* base, size_t v, float* d){
  if (BF16){
    const uint4* p = (const uint4*)((const u16*)base + v*F_);
    uint4 r0=p[0], r1=p[1];
    d[0]=bflo(r0.x); d[1]=bfhi(r0.x); d[2]=bflo(r0.y); d[3]=bfhi(r0.y);
    d[4]=bflo(r0.z); d[5]=bfhi(r0.z); d[6]=bflo(r0.w); d[7]=bfhi(r0.w);
    d[8]=bflo(r1.x); d[9]=bfhi(r1.x); d[10]=bflo(r1.y); d[11]=bfhi(r1.y);
    d[12]=bflo(r1.z); d[13]=bfhi(r1.z); d[14]=bflo(r1.w); d[15]=bfhi(r1.w);
  } else {
    const float4* p = (const float4*)((const float*)base + v*F_);
    float4 a=p[0], b=p[1], c=p[2], e=p[3];
    d[0]=a.x; d[1]=a.y; d[2]=a.z; d[3]=a.w;
    d[4]=b.x; d[5]=b.y; d[6]=b.z; d[7]=b.w;
    d[8]=c.x; d[9]=c.y; d[10]=c.z; d[11]=c.w;
    d[12]=e.x; d[13]=e.y; d[14]=e.z; d[15]=e.w;
  }
}

template<bool BF16>
__device__ __forceinline__ void fused_body(
    const void* __restrict__ data, const int* __restrict__ nv,
    const void* __restrict__ Wflr, const void* __restrict__ bflr,
    const void* __restrict__ Ws, const void* __restrict__ bs,
    const void* __restrict__ Wout, const void* __restrict__ bout,
    float* __restrict__ partial, uint32* __restrict__ flags,
    float* __restrict__ out)
{
  __shared__ __align__(16) float e_lds[VPB*ESTR];   // 24 KB, e[v][a], lives to end
  __shared__ __align__(16) float d_lds[256*DSTR];   // 20 KB, per-tile d[v][f]
  __shared__ __align__(16) float gred[32*GSL];      // 16.5 KB
  __shared__ float ered2[16*8];
  __shared__ float sGE[GE_];
  __shared__ float sagg[A_*P_];
  __shared__ __align__(16) float sM[A_*NF_];

  const int tid = threadIdx.x;
  const int bid = blockIdx.x;
  const int b = bid >> 3;
  const int s = bid & 7;
  const int nvb = nv[b];

  const int vbase = s*VPB;               // 512 vertices, 2 tiles of 256
  const size_t voff = (size_t)b*V_ + vbase;

  // phase-2 ownership: group g = (a-quad, f-quad), strided slice c
  const int g   = tid & 7;
  const int c   = tid >> 3;
  const int ga2 = g >> 2;
  const int gf  = g & 3;

  float4 acc0 = make_float4(0,0,0,0);
  float4 acc1 = make_float4(0,0,0,0);
  float4 acc2 = make_float4(0,0,0,0);
  float4 acc3 = make_float4(0,0,0,0);

  #pragma unroll
  for (int T=0; T<2; ++T) {
    // ---- phase 1: my vertex -> e[8] (weights via wave-uniform scalar path) ----
    const int vl = T*256 + tid;
    float d0[16];
    load_vertex<BF16>(data, voff+vl, d0);
    const float m = (vbase+vl < nvb) ? 1.f : 0.f;

    float t0[A_];
    #pragma unroll
    for (int a=0;a<A_;++a) t0[a] = ldw<BF16>(bs, a);
    #pragma unroll
    for (int f=0; f<F_; ++f){
      const float df = d0[f];
      #pragma unroll
      for (int a=0;a<A_;++a)
        t0[a] = fmaf(df, ldw<BF16>(Ws, f*A_+a), t0[a]);
    }
    float e0[A_];
    #pragma unroll
    for (int a=0;a<A_;++a) e0[a] = m*__expf(-t0[a]*t0[a]);

    float* er = &e_lds[vl*ESTR];         // persists across the barrier
    *(float4*)(er)   = make_float4(e0[0],e0[1],e0[2],e0[3]);
    *(float4*)(er+4) = make_float4(e0[4],e0[5],e0[6],e0[7]);
    float* dr = &d_lds[tid*DSTR];
    *(float4*)(dr)    = make_float4(d0[0],d0[1],d0[2],d0[3]);
    *(float4*)(dr+4)  = make_float4(d0[4],d0[5],d0[6],d0[7]);
    *(float4*)(dr+8)  = make_float4(d0[8],d0[9],d0[10],d0[11]);
    *(float4*)(dr+12) = make_float4(d0[12],d0[13],d0[14],d0[15]);
    __syncthreads();

    // ---- phase 2: (a-quad, f-quad) over 8 strided vertices: 2 b128 -> 16 FMA ----
    #pragma unroll
    for (int i=0;i<8;++i){
      const int v = c + (i<<5);
      const float4 e4 = *(const float4*)&e_lds[(T*256+v)*ESTR + ga2*4];
      const float4 d4 = *(const float4*)&d_lds[v*DSTR + gf*4];
      acc0.x = fmaf(e4.x, d4.x, acc0.x); acc0.y = fmaf(e4.x, d4.y, acc0.y);
      acc0.z = fmaf(e4.x, d4.z, acc0.z); acc0.w = fmaf(e4.x, d4.w, acc0.w);
      acc1.x = fmaf(e4.y, d4.x, acc1.x); acc1.y = fmaf(e4.y, d4.y, acc1.y);
      acc1.z = fmaf(e4.y, d4.z, acc1.z); acc1.w = fmaf(e4.y, d4.w, acc1.w);
      acc2.x = fmaf(e4.z, d4.x, acc2.x); acc2.y = fmaf(e4.z, d4.y, acc2.y);
      acc2.z = fmaf(e4.z, d4.z, acc2.z); acc2.w = fmaf(e4.z, d4.w, acc2.w);
      acc3.x = fmaf(e4.w, d4.x, acc3.x); acc3.y = fmaf(e4.w, d4.y, acc3.y);
      acc3.z = fmaf(e4.w, d4.z, acc3.z); acc3.w = fmaf(e4.w, d4.w, acc3.w);
    }
    __syncthreads();                     // d_lds reused next tile
  }

  // ---- block-local reductions ----
  {
    float* gb = &gred[c*GSL + g*16];
    *(float4*)(gb)    = acc0;
    *(float4*)(gb+4)  = acc1;
    *(float4*)(gb+8)  = acc2;
    *(float4*)(gb+12) = acc3;
  }
  __syncthreads();

  if (tid < 128){                        // G[a][f]: sum 32 slices (conflict-free)
    const int a = tid >> 4, f = tid & 15;
    const int gg = (a>>2)*4 + (f>>2);
    const int idx = (a&3)*4 + (f&3);
    float sum = 0.f;
    #pragma unroll 8
    for (int cc=0;cc<32;++cc) sum += gred[cc*GSL + gg*16 + idx];
    __hip_atomic_store(&partial[(size_t)bid*GE_ + a*F_ + f], sum,
                       __ATOMIC_RELAXED, __HIP_MEMORY_SCOPE_AGENT);
  } else {                               // E stage 1: scan e_lds cols, q-staggered
    const int t2 = tid - 128;
    const int q = t2 >> 3, a = t2 & 7;
    float sum = 0.f;
    #pragma unroll 8
    for (int i=0;i<32;++i){
      const int ii = (i + 2*q) & 31;     // stagger: spreads banks across q
      sum += e_lds[(q*32+ii)*ESTR + a];
    }
    ered2[q*8 + a] = sum;
  }
  __syncthreads();
  if (tid < A_){                         // E stage 2
    float sum = 0.f;
    #pragma unroll
    for (int q=0;q<16;++q) sum += ered2[q*8 + tid];
    __hip_atomic_store(&partial[(size_t)bid*GE_ + A_*F_ + tid], sum,
                       __ATOMIC_RELAXED, __HIP_MEMORY_SCOPE_AGENT);
  }
  __syncthreads();                       // drains vmcnt before barrier
  if (tid == 0)
    __hip_atomic_store(&flags[bid], MAGIC,
                       __ATOMIC_RELEASE, __HIP_MEMORY_SCOPE_AGENT);

  // ---- fan-in: RELAXED poll (no per-iter invalidate), bounded; then ONE fence ----
  if (tid < SPB) {
    const uint32* fp = &flags[b*SPB + tid];
    int it = 0;
    while (__hip_atomic_load(fp, __ATOMIC_RELAXED, __HIP_MEMORY_SCOPE_AGENT) != MAGIC) {
      if (++it > 500000) break;          // safety net: never hang
      __builtin_amdgcn_s_sleep(8);       // ~0.2 us per poll
    }
  }
  __syncthreads();
  __builtin_amdgcn_fence(__ATOMIC_ACQUIRE, "agent");   // single invalidate/block

  // ---- batch totals + tiny GEMMs ----
  if (tid < GE_) {
    float v = 0.f;
    #pragma unroll
    for (int k=0;k<SPB;++k)
      v += __hip_atomic_load(&partial[(size_t)(b*SPB+k)*GE_ + tid],
                             __ATOMIC_RELAXED, __HIP_MEMORY_SCOPE_AGENT);
    sGE[tid] = v;
  }
  __syncthreads();
  if (tid < A_*P_) {                     // agg[a,p]
    const int a = tid >> 4, p = tid & 15;
    float acc = sGE[A_*F_ + a] * ldw<BF16>(bflr, p);
    #pragma unroll
    for (int f=0;f<F_;++f) acc = fmaf(sGE[a*F_+f], ldw<BF16>(Wflr, f*P_+p), acc);
    sagg[tid] = acc * (1.0f/(float)V_);
  }
  __syncthreads();
  if (tid < A_*NF_) {                    // M[a,n]
    const int a = tid >> 4, n = tid & 15;
    float m = 0.f;
    #pragma unroll
    for (int p=0;p<P_;++p)
      m = fmaf(sagg[a*P_+p], ldw<BF16>(Wout, (a*P_+p)*NF_+n), m);
    sM[tid] = m;
  }
  __syncthreads();

  // ---- epilogue: stream e (LDS) -> out; M n-quad column cached in VGPRs ----
  const int vg = tid >> 2, nq = tid & 3;
  float4 Mq[A_];
  #pragma unroll
  for (int a=0;a<A_;++a) Mq[a] = *(const float4*)&sM[a*NF_ + nq*4];
  const float4 bo4 = make_float4(ldw<BF16>(bout,nq*4), ldw<BF16>(bout,nq*4+1),
                                 ldw<BF16>(bout,nq*4+2), ldw<BF16>(bout,nq*4+3));

  #pragma unroll
  for (int i=0;i<8;++i){
    const int vl = vg + (i<<6);
    const float m = (vbase+vl < nvb) ? 1.f : 0.f;
    const float4 ea = *(const float4*)&e_lds[vl*ESTR];     // 4 nq-lanes broadcast
    const float4 eb = *(const float4*)&e_lds[vl*ESTR + 4];

    float4 o = make_float4(m*bo4.x, m*bo4.y, m*bo4.z, m*bo4.w);
    o.x=fmaf(ea.x,Mq[0].x,o.x); o.y=fmaf(ea.x,Mq[0].y,o.y); o.z=fmaf(ea.x,Mq[0].z,o.z); o.w=fmaf(ea.x,Mq[0].w,o.w);
    o.x=fmaf(ea.y,Mq[1].x,o.x); o.y=fmaf(ea.y,Mq[1].y,o.y); o.z=fmaf(ea.y,Mq[1].z,o.z); o.w=fmaf(ea.y,Mq[1].w,o.w);
    o.x=fmaf(ea.z,Mq[2].x,o.x); o.y=fmaf(ea.z,Mq[2].y,o.y); o.z=fmaf(ea.z,Mq[2].z,o.z); o.w=fmaf(ea.z,Mq[2].w,o.w);
    o.x=fmaf(ea.w,Mq[3].x,o.x); o.y=fmaf(ea.w,Mq[3].y,o.y); o.z=fmaf(ea.w,Mq[3].z,o.z); o.w=fmaf(ea.w,Mq[3].w,o.w);
    o.x=fmaf(eb.x,Mq[4].x,o.x); o.y=fmaf(eb.x,Mq[4].y,o.y); o.z=fmaf(eb.x,Mq[4].z,o.z); o.w=fmaf(eb.x,Mq[4].w,o.w);
    o.x=fmaf(eb.y,Mq[5].x,o.x); o.y=fmaf(eb.y,Mq[5].y,o.y); o.z=fmaf(eb.y,Mq[5].z,o.z); o.w=fmaf(eb.y,Mq[5].w,o.w);
    o.x=fmaf(eb.z,Mq[6].x,o.x); o.y=fmaf(eb.z,Mq[6].y,o.y); o.z=fmaf(eb.z,Mq[6].z,o.z); o.w=fmaf(eb.z,Mq[6].w,o.w);
    o.x=fmaf(eb.w,Mq[7].x,o.x); o.y=fmaf(eb.w,Mq[7].y,o.y); o.z=fmaf(eb.w,Mq[7].z,o.z); o.w=fmaf(eb.w,Mq[7].w,o.w);

    *(float4*)(out + (voff+vl)*NF_ + nq*4) = o;   // nq fastest -> coalesced
  }
}

__global__ __launch_bounds__(256, 2) void k_fused(
    const void* __restrict__ data, const int* __restrict__ nv,
    const void* __restrict__ Wflr, const void* __restrict__ bflr,
    const void* __restrict__ Ws, const void* __restrict__ bs,
    const void* __restrict__ Wout, const void* __restrict__ bout,
    float* __restrict__ partial, uint32* __restrict__ flags,
    float* __restrict__ out)
{
  if (detect_bf16(data))
    fused_body<true >(data, nv, Wflr, bflr, Ws, bs, Wout, bout, partial, flags, out);
  else
    fused_body<false>(data, nv, Wflr, bflr, Ws, bs, Wout, bout, partial, flags, out);
}

extern "C" void kernel_launch(void* const* d_in, const int* in_sizes, int n_in,
                              void* d_out, int out_size, void* d_ws, size_t ws_size,
                              hipStream_t stream) {
  const void* data = d_in[0];
  const int*  nv   = (const int*)d_in[1];
  const void* Wflr = d_in[2];
  const void* bflr = d_in[3];
  const void* Ws   = d_in[4];
  const void* bs   = d_in[5];
  const void* Wout = d_in[6];
  const void* bout = d_in[7];
  float* out = (float*)d_out;
  float*  partial = (float*)d_ws;                              // 512*136*4 B
  uint32* flags   = (uint32*)((char*)d_ws + (size_t)NBLK*GE_*sizeof(float));
  // ws re-poisoned to 0xAA before every launch -> flags != MAGIC at entry.

  hipLaunchKernelGGL(k_fused, dim3(NBLK), dim3(256), 0, stream,
                     data, nv, Wflr, bflr, Ws, bs, Wout, bout,
                     partial, flags, out);
}

// Round 11
// 103.580 us; speedup vs baseline: 1.0956x; 1.0956x over previous
//
#include <hip/hip_runtime.h>

// GarNet: B=64 V=4096 F=16 A=8 P=16 NF=16. Inputs f32 (R2-confirmed), output f32.
// R10 lesson (LDS_Block_Size=128512): the <true>/<false> template instantiations
// each allocated their OWN static __shared__ arrays -> 2x LDS -> 1 block/CU ->
// half-machine serialization (57us kernel = 2 waves x 28.5). R11: single
// SharedMem struct declared once in the __global__ wrapper, passed by reference.
// Barrier design unchanged: 512 blocks = 2/CU co-resident, RELAXED poll +
// one agent acquire fence, bounded spin (never hangs).
//
//   G[b,a,f]=sum_v ew*d, E=sum_v ew ; agg=(Wflr^T G + bflr E)/V ; M=agg*Wout
//   out[v,n]= mask*bout[n] + sum_a ew[v,a]*M[a,n]      (e==0 when masked)

#define B_ 64
#define V_ 4096
#define F_ 16
#define A_ 8
#define P_ 16
#define NF_ 16
#define SPB 8                 // blocks per batch
#define NBLK (B_*SPB)         // 512 blocks = 2 per CU
#define VPB (V_/SPB)          // 512 vertices per block
#define GE_ (A_*F_ + A_)      // 136 partials per block
#define ESTR 12               // e_lds row stride (floats)
#define DSTR 20               // d_lds row stride (floats)
#define GSL 132               // gred slice stride (8 groups * 16 + 4 pad)
#define MAGIC 0x5CA1AB1Eu

typedef unsigned int uint32;
typedef unsigned short u16;

struct __align__(16) SharedMem {
  float e_lds[VPB*ESTR];      // 24 KB, e[v][a], lives to end
  float d_lds[256*DSTR];      // 20 KB, per-tile d[v][f]
  float gred[32*GSL];         // 16.5 KB
  float ered2[16*8];
  float sGE[GE_];
  float sagg[A_*P_];
  float sM[A_*NF_];
};                            // ~64 KB total -> 2 blocks/CU (160 KB budget)

__device__ __forceinline__ float bflo(uint32 u){ union{uint32 i;float f;}x; x.i=u<<16; return x.f; }
__device__ __forceinline__ float bfhi(uint32 u){ union{uint32 i;float f;}x; x.i=u&0xffff0000u; return x.f; }

// dtype probe (R2: votes f32 on this harness; kept as cheap insurance)
__device__ __forceinline__ bool detect_bf16(const void* data){
  const uint32* w = (const uint32*)data;
  int c = 0;
  #pragma unroll
  for (int i=0;i<16;++i){
    uint32 e = (w[i]>>7) & 0xffu;
    c += (e>=100u && e<=135u) ? 1 : 0;
  }
  return c >= 11;
}

template<bool BF16>
__device__ __forceinline__ float ldw(const void* p, int i){
  return BF16 ? bflo((uint32)((const u16*)p)[i]) : ((const float*)p)[i];
}

template<bool BF16>
__device__ __forceinline__ void load_vertex(const void* base, size_t v, float* d){
  if (BF16){
    const uint4* p = (const uint4*)((const u16*)base + v*F_);
    uint4 r0=p[0], r1=p[1];
    d[0]=bflo(r0.x); d[1]=bfhi(r0.x); d[2]=bflo(r0.y); d[3]=bfhi(r0.y);
    d[4]=bflo(r0.z); d[5]=bfhi(r0.z); d[6]=bflo(r0.w); d[7]=bfhi(r0.w);
    d[8]=bflo(r1.x); d[9]=bfhi(r1.x); d[10]=bflo(r1.y); d[11]=bfhi(r1.y);
    d[12]=bflo(r1.z); d[13]=bfhi(r1.z); d[14]=bflo(r1.w); d[15]=bfhi(r1.w);
  } else {
    const float4* p = (const float4*)((const float*)base + v*F_);
    float4 a=p[0], b=p[1], c=p[2], e=p[3];
    d[0]=a.x; d[1]=a.y; d[2]=a.z; d[3]=a.w;
    d[4]=b.x; d[5]=b.y; d[6]=b.z; d[7]=b.w;
    d[8]=c.x; d[9]=c.y; d[10]=c.z; d[11]=c.w;
    d[12]=e.x; d[13]=e.y; d[14]=e.z; d[15]=e.w;
  }
}

template<bool BF16>
__device__ __forceinline__ void fused_body(
    SharedMem& sm,
    const void* __restrict__ data, const int* __restrict__ nv,
    const void* __restrict__ Wflr, const void* __restrict__ bflr,
    const void* __restrict__ Ws, const void* __restrict__ bs,
    const void* __restrict__ Wout, const void* __restrict__ bout,
    float* __restrict__ partial, uint32* __restrict__ flags,
    float* __restrict__ out)
{
  const int tid = threadIdx.x;
  const int bid = blockIdx.x;
  const int b = bid >> 3;
  const int s = bid & 7;
  const int nvb = nv[b];

  const int vbase = s*VPB;               // 512 vertices, 2 tiles of 256
  const size_t voff = (size_t)b*V_ + vbase;

  // phase-2 ownership: group g = (a-quad, f-quad), strided slice c
  const int g   = tid & 7;
  const int c   = tid >> 3;
  const int ga2 = g >> 2;
  const int gf  = g & 3;

  float4 acc0 = make_float4(0,0,0,0);
  float4 acc1 = make_float4(0,0,0,0);
  float4 acc2 = make_float4(0,0,0,0);
  float4 acc3 = make_float4(0,0,0,0);

  #pragma unroll
  for (int T=0; T<2; ++T) {
    // ---- phase 1: my vertex -> e[8] (weights via wave-uniform scalar path) ----
    const int vl = T*256 + tid;
    float d0[16];
    load_vertex<BF16>(data, voff+vl, d0);
    const float m = (vbase+vl < nvb) ? 1.f : 0.f;

    float t0[A_];
    #pragma unroll
    for (int a=0;a<A_;++a) t0[a] = ldw<BF16>(bs, a);
    #pragma unroll
    for (int f=0; f<F_; ++f){
      const float df = d0[f];
      #pragma unroll
      for (int a=0;a<A_;++a)
        t0[a] = fmaf(df, ldw<BF16>(Ws, f*A_+a), t0[a]);
    }
    float e0[A_];
    #pragma unroll
    for (int a=0;a<A_;++a) e0[a] = m*__expf(-t0[a]*t0[a]);

    float* er = &sm.e_lds[vl*ESTR];      // persists across the barrier
    *(float4*)(er)   = make_float4(e0[0],e0[1],e0[2],e0[3]);
    *(float4*)(er+4) = make_float4(e0[4],e0[5],e0[6],e0[7]);
    float* dr = &sm.d_lds[tid*DSTR];
    *(float4*)(dr)    = make_float4(d0[0],d0[1],d0[2],d0[3]);
    *(float4*)(dr+4)  = make_float4(d0[4],d0[5],d0[6],d0[7]);
    *(float4*)(dr+8)  = make_float4(d0[8],d0[9],d0[10],d0[11]);
    *(float4*)(dr+12) = make_float4(d0[12],d0[13],d0[14],d0[15]);
    __syncthreads();

    // ---- phase 2: (a-quad, f-quad) over 8 strided vertices: 2 b128 -> 16 FMA ----
    #pragma unroll
    for (int i=0;i<8;++i){
      const int v = c + (i<<5);
      const float4 e4 = *(const float4*)&sm.e_lds[(T*256+v)*ESTR + ga2*4];
      const float4 d4 = *(const float4*)&sm.d_lds[v*DSTR + gf*4];
      acc0.x = fmaf(e4.x, d4.x, acc0.x); acc0.y = fmaf(e4.x, d4.y, acc0.y);
      acc0.z = fmaf(e4.x, d4.z, acc0.z); acc0.w = fmaf(e4.x, d4.w, acc0.w);
      acc1.x = fmaf(e4.y, d4.x, acc1.x); acc1.y = fmaf(e4.y, d4.y, acc1.y);
      acc1.z = fmaf(e4.y, d4.z, acc1.z); acc1.w = fmaf(e4.y, d4.w, acc1.w);
      acc2.x = fmaf(e4.z, d4.x, acc2.x); acc2.y = fmaf(e4.z, d4.y, acc2.y);
      acc2.z = fmaf(e4.z, d4.z, acc2.z); acc2.w = fmaf(e4.z, d4.w, acc2.w);
      acc3.x = fmaf(e4.w, d4.x, acc3.x); acc3.y = fmaf(e4.w, d4.y, acc3.y);
      acc3.z = fmaf(e4.w, d4.z, acc3.z); acc3.w = fmaf(e4.w, d4.w, acc3.w);
    }
    __syncthreads();                     // d_lds reused next tile
  }

  // ---- block-local reductions ----
  {
    float* gb = &sm.gred[c*GSL + g*16];
    *(float4*)(gb)    = acc0;
    *(float4*)(gb+4)  = acc1;
    *(float4*)(gb+8)  = acc2;
    *(float4*)(gb+12) = acc3;
  }
  __syncthreads();

  if (tid < 128){                        // G[a][f]: sum 32 slices
    const int a = tid >> 4, f = tid & 15;
    const int gg = (a>>2)*4 + (f>>2);
    const int idx = (a&3)*4 + (f&3);
    float sum = 0.f;
    #pragma unroll 8
    for (int cc=0;cc<32;++cc) sum += sm.gred[cc*GSL + gg*16 + idx];
    __hip_atomic_store(&partial[(size_t)bid*GE_ + a*F_ + f], sum,
                       __ATOMIC_RELAXED, __HIP_MEMORY_SCOPE_AGENT);
  } else {                               // E stage 1: scan e_lds cols, q-staggered
    const int t2 = tid - 128;
    const int q = t2 >> 3, a = t2 & 7;
    float sum = 0.f;
    #pragma unroll 8
    for (int i=0;i<32;++i){
      const int ii = (i + 2*q) & 31;
      sum += sm.e_lds[(q*32+ii)*ESTR + a];
    }
    sm.ered2[q*8 + a] = sum;
  }
  __syncthreads();
  if (tid < A_){                         // E stage 2
    float sum = 0.f;
    #pragma unroll
    for (int q=0;q<16;++q) sum += sm.ered2[q*8 + tid];
    __hip_atomic_store(&partial[(size_t)bid*GE_ + A_*F_ + tid], sum,
                       __ATOMIC_RELAXED, __HIP_MEMORY_SCOPE_AGENT);
  }
  __syncthreads();                       // drains vmcnt before barrier
  if (tid == 0)
    __hip_atomic_store(&flags[bid], MAGIC,
                       __ATOMIC_RELEASE, __HIP_MEMORY_SCOPE_AGENT);

  // ---- fan-in: RELAXED poll, bounded; then ONE acquire fence ----
  if (tid < SPB) {
    const uint32* fp = &flags[b*SPB + tid];
    int it = 0;
    while (__hip_atomic_load(fp, __ATOMIC_RELAXED, __HIP_MEMORY_SCOPE_AGENT) != MAGIC) {
      if (++it > 1000000) break;         // safety net: never hang
      __builtin_amdgcn_s_sleep(2);
    }
  }
  __syncthreads();
  __builtin_amdgcn_fence(__ATOMIC_ACQUIRE, "agent");   // single invalidate/block

  // ---- batch totals + tiny GEMMs ----
  if (tid < GE_) {
    float v = 0.f;
    #pragma unroll
    for (int k=0;k<SPB;++k)
      v += __hip_atomic_load(&partial[(size_t)(b*SPB+k)*GE_ + tid],
                             __ATOMIC_RELAXED, __HIP_MEMORY_SCOPE_AGENT);
    sm.sGE[tid] = v;
  }
  __syncthreads();
  if (tid < A_*P_) {                     // agg[a,p]
    const int a = tid >> 4, p = tid & 15;
    float acc = sm.sGE[A_*F_ + a] * ldw<BF16>(bflr, p);
    #pragma unroll
    for (int f=0;f<F_;++f) acc = fmaf(sm.sGE[a*F_+f], ldw<BF16>(Wflr, f*P_+p), acc);
    sm.sagg[tid] = acc * (1.0f/(float)V_);
  }
  __syncthreads();
  if (tid < A_*NF_) {                    // M[a,n]
    const int a = tid >> 4, n = tid & 15;
    float m = 0.f;
    #pragma unroll
    for (int p=0;p<P_;++p)
      m = fmaf(sm.sagg[a*P_+p], ldw<BF16>(Wout, (a*P_+p)*NF_+n), m);
    sm.sM[tid] = m;
  }
  __syncthreads();

  // ---- epilogue: stream e (LDS) -> out; M n-quad column cached in VGPRs ----
  const int vg = tid >> 2, nq = tid & 3;
  float4 Mq[A_];
  #pragma unroll
  for (int a=0;a<A_;++a) Mq[a] = *(const float4*)&sm.sM[a*NF_ + nq*4];
  const float4 bo4 = make_float4(ldw<BF16>(bout,nq*4), ldw<BF16>(bout,nq*4+1),
                                 ldw<BF16>(bout,nq*4+2), ldw<BF16>(bout,nq*4+3));

  #pragma unroll
  for (int i=0;i<8;++i){
    const int vl = vg + (i<<6);
    const float m = (vbase+vl < nvb) ? 1.f : 0.f;
    const float4 ea = *(const float4*)&sm.e_lds[vl*ESTR];
    const float4 eb = *(const float4*)&sm.e_lds[vl*ESTR + 4];

    float4 o = make_float4(m*bo4.x, m*bo4.y, m*bo4.z, m*bo4.w);
    o.x=fmaf(ea.x,Mq[0].x,o.x); o.y=fmaf(ea.x,Mq[0].y,o.y); o.z=fmaf(ea.x,Mq[0].z,o.z); o.w=fmaf(ea.x,Mq[0].w,o.w);
    o.x=fmaf(ea.y,Mq[1].x,o.x); o.y=fmaf(ea.y,Mq[1].y,o.y); o.z=fmaf(ea.y,Mq[1].z,o.z); o.w=fmaf(ea.y,Mq[1].w,o.w);
    o.x=fmaf(ea.z,Mq[2].x,o.x); o.y=fmaf(ea.z,Mq[2].y,o.y); o.z=fmaf(ea.z,Mq[2].z,o.z); o.w=fmaf(ea.z,Mq[2].w,o.w);
    o.x=fmaf(ea.w,Mq[3].x,o.x); o.y=fmaf(ea.w,Mq[3].y,o.y); o.z=fmaf(ea.w,Mq[3].z,o.z); o.w=fmaf(ea.w,Mq[3].w,o.w);
    o.x=fmaf(eb.x,Mq[4].x,o.x); o.y=fmaf(eb.x,Mq[4].y,o.y); o.z=fmaf(eb.x,Mq[4].z,o.z); o.w=fmaf(eb.x,Mq[4].w,o.w);
    o.x=fmaf(eb.y,Mq[5].x,o.x); o.y=fmaf(eb.y,Mq[5].y,o.y); o.z=fmaf(eb.y,Mq[5].z,o.z); o.w=fmaf(eb.y,Mq[5].w,o.w);
    o.x=fmaf(eb.z,Mq[6].x,o.x); o.y=fmaf(eb.z,Mq[6].y,o.y); o.z=fmaf(eb.z,Mq[6].z,o.z); o.w=fmaf(eb.z,Mq[6].w,o.w);
    o.x=fmaf(eb.w,Mq[7].x,o.x); o.y=fmaf(eb.w,Mq[7].y,o.y); o.z=fmaf(eb.w,Mq[7].z,o.z); o.w=fmaf(eb.w,Mq[7].w,o.w);

    *(float4*)(out + (voff+vl)*NF_ + nq*4) = o;   // nq fastest -> coalesced
  }
}

__global__ __launch_bounds__(256, 2) void k_fused(
    const void* __restrict__ data, const int* __restrict__ nv,
    const void* __restrict__ Wflr, const void* __restrict__ bflr,
    const void* __restrict__ Ws, const void* __restrict__ bs,
    const void* __restrict__ Wout, const void* __restrict__ bout,
    float* __restrict__ partial, uint32* __restrict__ flags,
    float* __restrict__ out)
{
  __shared__ SharedMem sm;               // single allocation for BOTH instantiations
  if (detect_bf16(data))
    fused_body<true >(sm, data, nv, Wflr, bflr, Ws, bs, Wout, bout, partial, flags, out);
  else
    fused_body<false>(sm, data, nv, Wflr, bflr, Ws, bs, Wout, bout, partial, flags, out);
}

extern "C" void kernel_launch(void* const* d_in, const int* in_sizes, int n_in,
                              void* d_out, int out_size, void* d_ws, size_t ws_size,
                              hipStream_t stream) {
  const void* data = d_in[0];
  const int*  nv   = (const int*)d_in[1];
  const void* Wflr = d_in[2];
  const void* bflr = d_in[3];
  const void* Ws   = d_in[4];
  const void* bs   = d_in[5];
  const void* Wout = d_in[6];
  const void* bout = d_in[7];
  float* out = (float*)d_out;
  float*  partial = (float*)d_ws;                              // 512*136*4 B
  uint32* flags   = (uint32*)((char*)d_ws + (size_t)NBLK*GE_*sizeof(float));
  // ws re-poisoned to 0xAA before every launch -> flags != MAGIC at entry.

  hipLaunchKernelGGL(k_fused, dim3(NBLK), dim3(256), 0, stream,
                     data, nv, Wflr, bflr, Ws, bs, Wout, bout,
                     partial, flags, out);
}

// Round 12
// 93.838 us; speedup vs baseline: 1.2093x; 1.1038x over previous
//
#include <hip/hip_runtime.h>

// GarNet: B=64 V=4096 F=16 A=8 P=16 NF=16. Inputs f32 (R2-confirmed), output f32.
// FINAL STRUCTURE (= R7, measured best 94.3us): two kernels.
//  - k_agg: per-(batch,split) block computes e[v][8]=mask*exp(-(d@Ws+bs)^2),
//    caches it (u16 fixed-point, abs err 7.6e-6) in ws, and accumulates
//    G[a,f]=sum_v e*d, E[a]=sum_v e via LDS ownership decomposition
//    (no cross-lane shuffles: R4 showed 816 ds-shuffles under register
//    pressure = ~45us stall; R5/R6 fixed with LDS trees).
//  - k_out: folds agg=(Wflr^T G + bflr E)/V and M=agg@Wout per batch in-block,
//    then streams ecache -> out with M cached in VGPRs, coalesced float4 writes.
// Fusion with a grid fan-in barrier was tried 3x (R9-R11): always ~10us WORSE —
// the barrier gates every batch on the 512-block dispatch ramp, which the
// two-kernel pipeline hides. Launch overhead (2 x ~5us) + ~11us kernel work
// lands within ~10% of the achievable floor given ~71us fixed harness resets.
//
//   G[b,a,f]=sum_v ew*d, E=sum_v ew ; agg=(Wflr^T G + bflr E)/V ; M=agg*Wout
//   out[v,n]= mask*bout[n] + sum_a ew[v,a]*M[a,n]      (cached ew==0 when masked)

#define B_ 64
#define V_ 4096
#define F_ 16
#define A_ 8
#define P_ 16
#define NF_ 16
#define SPLIT1 8              // k_agg: 8 blocks/batch -> 512 blocks
#define SPLIT2 16             // k_out: 16 blocks/batch -> 1024 blocks
#define GE_ (A_*F_ + A_)      // 136 partials per k_agg block
#define ESTR 12               // e_lds row stride (16B-aligned writes, 2-way banks)
#define DSTR 20               // d_lds row stride (16B-aligned b128, 2-way banks)

typedef unsigned int uint32;
typedef unsigned short u16;

__device__ __forceinline__ float bflo(uint32 u){ union{uint32 i;float f;}x; x.i=u<<16; return x.f; }
__device__ __forceinline__ float bfhi(uint32 u){ union{uint32 i;float f;}x; x.i=u&0xffff0000u; return x.f; }

// dtype probe (R2: votes f32 on this harness; kept as cheap insurance)
__device__ __forceinline__ bool detect_bf16(const void* data){
  const uint32* w = (const uint32*)data;
  int c = 0;
  #pragma unroll
  for (int i=0;i<16;++i){
    uint32 e = (w[i]>>7) & 0xffu;
    c += (e>=100u && e<=135u) ? 1 : 0;
  }
  return c >= 11;
}

template<bool BF16>
__device__ __forceinline__ float ldw(const void* p, int i){
  return BF16 ? bflo((uint32)((const u16*)p)[i]) : ((const float*)p)[i];
}

template<bool BF16>
__device__ __forceinline__ void load_vertex(const void* base, size_t v, float* d){
  if (BF16){
    const uint4* p = (const uint4*)((const u16*)base + v*F_);
    uint4 r0=p[0], r1=p[1];
    d[0]=bflo(r0.x); d[1]=bfhi(r0.x); d[2]=bflo(r0.y); d[3]=bfhi(r0.y);
    d[4]=bflo(r0.z); d[5]=bfhi(r0.z); d[6]=bflo(r0.w); d[7]=bfhi(r0.w);
    d[8]=bflo(r1.x); d[9]=bfhi(r1.x); d[10]=bflo(r1.y); d[11]=bfhi(r1.y);
    d[12]=bflo(r1.z); d[13]=bfhi(r1.z); d[14]=bflo(r1.w); d[15]=bfhi(r1.w);
  } else {
    const float4* p = (const float4*)((const float*)base + v*F_);
    float4 a=p[0], b=p[1], c=p[2], e=p[3];
    d[0]=a.x; d[1]=a.y; d[2]=a.z; d[3]=a.w;
    d[4]=b.x; d[5]=b.y; d[6]=b.z; d[7]=b.w;
    d[8]=c.x; d[9]=c.y; d[10]=c.z; d[11]=c.w;
    d[12]=e.x; d[13]=e.y; d[14]=e.z; d[15]=e.w;
  }
}

// ---------------- Kernel A: G[a,f], E[a] per (batch, split); cache e ----------------
template<bool BF16>
__device__ __forceinline__ void agg_body(
    const void* __restrict__ data, const int* __restrict__ nv,
    const void* __restrict__ Ws, const void* __restrict__ bs,
    float* __restrict__ partial, uint4* __restrict__ ecache)
{
  __shared__ __align__(16) float sWs[F_*A_];
  __shared__ float sbs[A_];
  __shared__ __align__(16) float e_lds[256*ESTR];   // 12 KB, e[v][a]
  __shared__ __align__(16) float d_lds[256*DSTR];   // 20 KB, d[v][f]
  __shared__ __align__(16) float gred[8*32*4];      // 4 KB, [chunk][group]x4
  __shared__ float ered2[16*8];                     // E partial stage

  const int tid = threadIdx.x;
  if (tid < F_*A_) sWs[tid] = ldw<BF16>(Ws, tid);
  if (tid < A_)    sbs[tid] = ldw<BF16>(bs, tid);
  const int b = blockIdx.x >> 3;
  const int s = blockIdx.x & 7;
  const int nvb = nv[b];
  __syncthreads();

  const int vbase = s*(V_/SPLIT1);       // 512 vertices per block, 2 tiles of 256
  const size_t voff = (size_t)b*V_ + vbase;

  // ownership: group g = (a, f-quad), chunk c = 32-vertex slice
  const int g  = tid & 31;
  const int c  = tid >> 5;
  const int ga = g >> 2;
  const int gf = g & 3;

  float acc0=0.f, acc1=0.f, acc2=0.f, acc3=0.f;   // G[ga][gf*4..+3]
  float E[A_];
  #pragma unroll
  for (int a=0;a<A_;++a) E[a]=0.f;

  #pragma unroll
  for (int T=0; T<2; ++T) {
    // ---- phase 1: my vertex -> e[8], stash e,d in LDS + e-cache to ws ----
    const int vl = T*256 + tid;
    float d0[16];
    load_vertex<BF16>(data, voff+vl, d0);
    const float m = (vbase+vl < nvb) ? 1.f : 0.f;

    float t0[A_];
    #pragma unroll
    for (int a=0;a<A_;++a) t0[a]=sbs[a];
    #pragma unroll
    for (int f=0; f<F_; ++f){
      const float4 w0 = *(const float4*)&sWs[f*A_];
      const float4 w1 = *(const float4*)&sWs[f*A_+4];
      const float wa[8] = {w0.x,w0.y,w0.z,w0.w,w1.x,w1.y,w1.z,w1.w};
      #pragma unroll
      for (int a=0;a<A_;++a) t0[a] = fmaf(d0[f], wa[a], t0[a]);
    }
    float e0[A_];
    #pragma unroll
    for (int a=0;a<A_;++a){
      e0[a] = m*__expf(-t0[a]*t0[a]);
      E[a] += e0[a];
    }
    {   // e-cache: u16 fixed-point, e in [0,1] -> abs err <= 0.5/65535
      const uint32 q0 = __float2uint_rn(e0[0]*65535.f) | (__float2uint_rn(e0[1]*65535.f)<<16);
      const uint32 q1 = __float2uint_rn(e0[2]*65535.f) | (__float2uint_rn(e0[3]*65535.f)<<16);
      const uint32 q2 = __float2uint_rn(e0[4]*65535.f) | (__float2uint_rn(e0[5]*65535.f)<<16);
      const uint32 q3 = __float2uint_rn(e0[6]*65535.f) | (__float2uint_rn(e0[7]*65535.f)<<16);
      ecache[voff+vl] = make_uint4(q0,q1,q2,q3);
    }
    float* er = &e_lds[tid*ESTR];
    *(float4*)(er)   = make_float4(e0[0],e0[1],e0[2],e0[3]);
    *(float4*)(er+4) = make_float4(e0[4],e0[5],e0[6],e0[7]);
    float* dr = &d_lds[tid*DSTR];
    *(float4*)(dr)    = make_float4(d0[0],d0[1],d0[2],d0[3]);
    *(float4*)(dr+4)  = make_float4(d0[4],d0[5],d0[6],d0[7]);
    *(float4*)(dr+8)  = make_float4(d0[8],d0[9],d0[10],d0[11]);
    *(float4*)(dr+12) = make_float4(d0[12],d0[13],d0[14],d0[15]);
    __syncthreads();

    // ---- phase 2: accumulate my (a,f-quad) over my 32-vertex chunk ----
    const float* ep = &e_lds[(c<<5)*ESTR + ga];
    const float* dp = &d_lds[(c<<5)*DSTR + gf*4];
    #pragma unroll 8
    for (int i=0;i<32;++i){
      const float e  = ep[i*ESTR];
      const float4 dv = *(const float4*)(dp + i*DSTR);
      acc0 = fmaf(e, dv.x, acc0);
      acc1 = fmaf(e, dv.y, acc1);
      acc2 = fmaf(e, dv.z, acc2);
      acc3 = fmaf(e, dv.w, acc3);
    }
    __syncthreads();                               // LDS reused next tile
  }

  // ---- reductions ----
  *(float4*)&gred[(c*32+g)*4] = make_float4(acc0,acc1,acc2,acc3);
  float* er = &e_lds[tid*ESTR];
  *(float4*)(er)   = make_float4(E[0],E[1],E[2],E[3]);
  *(float4*)(er+4) = make_float4(E[4],E[5],E[6],E[7]);
  __syncthreads();

  if (tid < 128){                        // G: (group, f-in-quad) -> sum 8 chunks
    const int gg = tid >> 2, fi = tid & 3;
    float sum = 0.f;
    #pragma unroll
    for (int k=0;k<8;++k) sum += gred[(k*32+gg)*4 + fi];
    partial[(size_t)blockIdx.x*GE_ + (gg>>2)*F_ + (gg&3)*4 + fi] = sum;
  } else {                               // E stage 1
    const int t2 = tid - 128;
    const int q = t2 >> 3, a = t2 & 7;
    float sum = 0.f;
    #pragma unroll
    for (int i=0;i<16;++i) sum += e_lds[(q*16+i)*ESTR + a];
    ered2[q*8 + a] = sum;
  }
  __syncthreads();
  if (tid < A_){                         // E stage 2
    float sum = 0.f;
    #pragma unroll
    for (int q=0;q<16;++q) sum += ered2[q*8 + tid];
    partial[(size_t)blockIdx.x*GE_ + A_*F_ + tid] = sum;
  }
}

__global__ __launch_bounds__(256, 4) void k_agg(
    const void* __restrict__ data, const int* __restrict__ nv,
    const void* __restrict__ Ws, const void* __restrict__ bs,
    float* __restrict__ partial, uint4* __restrict__ ecache)
{
  if (detect_bf16(data)) agg_body<true >(data, nv, Ws, bs, partial, ecache);
  else                   agg_body<false>(data, nv, Ws, bs, partial, ecache);
}

// ------------- Kernel B: agg->M per batch, read e-cache, emit f32 out -------------
template<bool BF16>
__device__ __forceinline__ void out_body(
    const int* __restrict__ nv,
    const void* __restrict__ Wflr, const void* __restrict__ bflr,
    const void* __restrict__ Wout, const void* __restrict__ bout,
    const float* __restrict__ partial, const uint4* __restrict__ ecache,
    float* __restrict__ out)
{
  __shared__ __align__(16) float sWf[F_*P_];
  __shared__ __align__(16) float sWo[A_*P_*NF_];   // 8 KB staged Wout
  __shared__ float sbf[P_], sbo[NF_];
  __shared__ float sGE[GE_];
  __shared__ float sagg[A_*P_];
  __shared__ __align__(16) float sM[A_*NF_];

  const int tid = threadIdx.x;
  const int b = blockIdx.x >> 4;
  const int s = blockIdx.x & 15;

  sWf[tid] = ldw<BF16>(Wflr, tid);                 // F*P == 256
  #pragma unroll
  for (int j=0;j<8;++j)
    sWo[tid*8+j] = ldw<BF16>(Wout, tid*8+j);
  if (tid < P_)  sbf[tid] = ldw<BF16>(bflr, tid);
  if (tid < NF_) sbo[tid] = ldw<BF16>(bout, tid);
  if (tid < GE_) {
    const float* pp = partial + (size_t)(b*SPLIT1)*GE_ + tid;
    float v = 0.f;
    #pragma unroll
    for (int k=0;k<SPLIT1;++k) v += pp[(size_t)k*GE_];
    sGE[tid] = v;
  }
  const int nvb = nv[b];
  __syncthreads();

  if (tid < A_*P_) {                     // agg[a,p]
    const int a = tid >> 4, p = tid & 15;
    float acc = sGE[A_*F_ + a] * sbf[p];
    #pragma unroll
    for (int f=0;f<F_;++f) acc = fmaf(sGE[a*F_+f], sWf[f*P_+p], acc);
    sagg[tid] = acc * (1.0f/(float)V_);
  }
  __syncthreads();
  if (tid < A_*NF_) {                    // M[a,n]
    const int a = tid >> 4, n = tid & 15;
    float m = 0.f;
    #pragma unroll
    for (int p=0;p<P_;++p)
      m = fmaf(sagg[a*P_+p], sWo[(a*P_+p)*NF_+n], m);
    sM[tid] = m;
  }
  __syncthreads();

  // 1 vertex per thread: read cached e, emit out
  const int vbase = s*(V_/SPLIT2);       // 256 vertices per block
  const int vl = tid;
  const size_t v = (size_t)b*V_ + vbase + vl;
  const float m = (vbase+vl < nvb) ? 1.f : 0.f;

  const uint4 eu = ecache[v];
  const float k16 = 1.0f/65535.f;
  float e0[A_];
  e0[0] = (float)(eu.x & 0xffffu)*k16;  e0[1] = (float)(eu.x >> 16)*k16;
  e0[2] = (float)(eu.y & 0xffffu)*k16;  e0[3] = (float)(eu.y >> 16)*k16;
  e0[4] = (float)(eu.z & 0xffffu)*k16;  e0[5] = (float)(eu.z >> 16)*k16;
  e0[6] = (float)(eu.w & 0xffffu)*k16;  e0[7] = (float)(eu.w >> 16)*k16;

  float o[NF_];
  #pragma unroll
  for (int n=0;n<NF_;++n) o[n] = m*sbo[n];         // e pre-masked; only bias needs m
  #pragma unroll
  for (int a=0;a<A_;++a){
    const float e = e0[a];
    const float4 q0 = *(const float4*)&sM[a*NF_];
    const float4 q1 = *(const float4*)&sM[a*NF_+4];
    const float4 q2 = *(const float4*)&sM[a*NF_+8];
    const float4 q3 = *(const float4*)&sM[a*NF_+12];
    const float ma[16] = {q0.x,q0.y,q0.z,q0.w, q1.x,q1.y,q1.z,q1.w,
                          q2.x,q2.y,q2.z,q2.w, q3.x,q3.y,q3.z,q3.w};
    #pragma unroll
    for (int n=0;n<NF_;++n) o[n] = fmaf(e, ma[n], o[n]);
  }

  float4* ob = (float4*)(out + v*NF_);
  ob[0] = make_float4(o[0],  o[1],  o[2],  o[3]);
  ob[1] = make_float4(o[4],  o[5],  o[6],  o[7]);
  ob[2] = make_float4(o[8],  o[9],  o[10], o[11]);
  ob[3] = make_float4(o[12], o[13], o[14], o[15]);
}

__global__ __launch_bounds__(256, 4) void k_out(
    const void* __restrict__ data, const int* __restrict__ nv,
    const void* __restrict__ Wflr, const void* __restrict__ bflr,
    const void* __restrict__ Wout, const void* __restrict__ bout,
    const float* __restrict__ partial, const uint4* __restrict__ ecache,
    float* __restrict__ out)
{
  if (detect_bf16(data))
    out_body<true >(nv, Wflr, bflr, Wout, bout, partial, ecache, out);
  else
    out_body<false>(nv, Wflr, bflr, Wout, bout, partial, ecache, out);
}

extern "C" void kernel_launch(void* const* d_in, const int* in_sizes, int n_in,
                              void* d_out, int out_size, void* d_ws, size_t ws_size,
                              hipStream_t stream) {
  const void* data = d_in[0];
  const int*  nv   = (const int*)d_in[1];
  const void* Wflr = d_in[2];
  const void* bflr = d_in[3];
  const void* Ws   = d_in[4];
  const void* bs   = d_in[5];
  const void* Wout = d_in[6];
  const void* bout = d_in[7];
  float* out = (float*)d_out;
  float* partial = (float*)d_ws;                   // 512*136*4 = 278528 B
  uint4* ecache  = (uint4*)((char*)d_ws + 278528); // 4 MiB, 16B-aligned
  // both regions fully overwritten by k_agg each launch (no init needed)

  hipLaunchKernelGGL(k_agg, dim3(B_*SPLIT1), dim3(256), 0, stream,
                     data, nv, Ws, bs, partial, ecache);
  hipLaunchKernelGGL(k_out, dim3(B_*SPLIT2), dim3(256), 0, stream,
                     data, nv, Wflr, bflr, Wout, bout, partial, ecache, out);
}